// Round 5
// baseline (345.288 us; speedup 1.0000x reference)
//
#include <hip/hip_runtime.h>
#include <stdint.h>

#define DIM     300
#define NBATCH  4096
#define RTOK    32
#define NSUP    64      // N*S = 2*32 support cols
#define KP      320     // K padded to 10*32
#define NKS     10      // K steps of 32
#define GRID    768     // persistent blocks: 3 per CU
#define ASTRIDE 328     // LDS row stride (ushort) for A tiles (16B-aligned rows)
#define SMST    82      // padded sm tile x-stride (floats)
#define SMY     36      // per-channel y extent

typedef float f32x4 __attribute__((ext_vector_type(4)));
typedef short s16x8 __attribute__((ext_vector_type(8)));

static __device__ __forceinline__ unsigned bc(float x) { return __builtin_bit_cast(unsigned, x); }
static __device__ __forceinline__ float asf(unsigned u) { return __builtin_bit_cast(float, u); }
static __device__ __forceinline__ unsigned perm_hi(unsigned a, unsigned b) {
    return __builtin_amdgcn_perm(a, b, 0x07060302u);   // [a.hi16 : b.hi16]
}
static __device__ __forceinline__ unsigned short f2bf(float x) {   // RNE (prep only)
    unsigned u = bc(x);
    return (unsigned short)((u + 0x7FFFu + ((u >> 16) & 1u)) >> 16);
}
static __device__ __forceinline__ float bf2f(unsigned short h) { return asf((unsigned)h << 16); }

// ---------------- kernel 1: normalize support vectors -> bf16 hi/lo [64][320]
__global__ __launch_bounds__(64) void prep_kernel(
    const int* __restrict__ sidx, const float* __restrict__ emb,
    unsigned short* __restrict__ Bh, unsigned short* __restrict__ Bl) {
    const int j = blockIdx.x, l = threadIdx.x;
    const size_t tok = (size_t)sidx[j];
    const float* src = emb + tok * DIM;
    float e[5];
    #pragma unroll
    for (int c = 0; c < 5; ++c) {
        const int k = c * 64 + l;
        e[c] = (k < DIM) ? src[k] : 0.f;
    }
    float s = e[0]*e[0] + e[1]*e[1] + e[2]*e[2] + e[3]*e[3] + e[4]*e[4];
    #pragma unroll
    for (int m = 32; m >= 1; m >>= 1) s += __shfl_xor(s, m);
    const float rn = 1.f / fmaxf(sqrtf(s), 1e-8f);
    #pragma unroll
    for (int c = 0; c < 5; ++c) {
        const int k = c * 64 + l;
        const float v = (k < DIM) ? e[c] * rn : 0.f;
        const unsigned short h = f2bf(v);
        Bh[j * KP + k] = h;
        Bl[j * KP + k] = f2bf(v - bf2f(h));
    }
}

// ---------------- kernel 2: persistent fused pipeline
__global__ __launch_bounds__(512, 6) void main_kernel(
    const int* __restrict__ tokens, const float* __restrict__ emb,
    const unsigned short* __restrict__ Bh, const unsigned short* __restrict__ Bl,
    const float* __restrict__ c1w, const float* __restrict__ c1b,
    const float* __restrict__ c2w, const float* __restrict__ c2b,
    const float* __restrict__ f2w, const float* __restrict__ f2b,
    const float* __restrict__ fcw, const float* __restrict__ fcb,
    float* __restrict__ out) {

    __shared__ __attribute__((aligned(16))) unsigned short Ah[32 * ASTRIDE];
    __shared__ __attribute__((aligned(16))) unsigned short Al[32 * ASTRIDE];
    __shared__ __attribute__((aligned(16))) float smP[34 * SMST];
    __shared__ __attribute__((aligned(16))) float norms[32];
    __shared__ __attribute__((aligned(16))) float scrP[16];   // [0..7]=se_w, [8..15]=sv_w
    __shared__ float scr2[4];                                 // fc partials
    float* pl1P = (float*)Ah;   // overlay: [2][17][18] zero-bordered pool1

    const int tid = threadIdx.x;
    const int w = tid >> 6, l = tid & 63;
    const int cb = (w & 3) * 16, rb = (w >> 2) * 16;
    const int c = l & 15, hq = l >> 4;
    const int row0 = w * 4;
    const bool tl = (l < DIM - 256);
    const int ch = (w & 3) >> 1;            // softmax channel of this wave's tile
    const int oc = tid >> 8, ii = (tid >> 4) & 15, jj = tid & 15;

    // zero smP ONCE (borders stay zero forever; interior rewritten per batch)
    {
        const f32x4 z = {0.f, 0.f, 0.f, 0.f};
        ((f32x4*)smP)[tid] = z;
        if (tid < 697 - 512) ((f32x4*)smP)[512 + tid] = z;
    }

    float4 e4[4]; float et[4];
    // prologue gather for first batch
    {
        const int b = blockIdx.x;
        #pragma unroll
        for (int rr = 0; rr < 4; ++rr) {
            const size_t tok = (size_t)tokens[b * RTOK + row0 + rr];
            const float* src = emb + tok * DIM;
            e4[rr] = *(const float4*)(src + 4 * l);
            et[rr] = tl ? src[256 + l] : 0.f;
        }
    }

    for (int bi = blockIdx.x; bi < NBATCH; bi += GRID) {
        // ---- P0: pack current batch's raw rows -> split-bf16 A tiles
        #pragma unroll
        for (int rr = 0; rr < 4; ++rr) {
            const int row = row0 + rr;
            const unsigned u0 = bc(e4[rr].x) + 0x8000u, u1 = bc(e4[rr].y) + 0x8000u;
            const unsigned u2 = bc(e4[rr].z) + 0x8000u, u3 = bc(e4[rr].w) + 0x8000u;
            const float r0 = e4[rr].x - asf(u0 & 0xffff0000u);
            const float r1 = e4[rr].y - asf(u1 & 0xffff0000u);
            const float r2 = e4[rr].z - asf(u2 & 0xffff0000u);
            const float r3 = e4[rr].w - asf(u3 & 0xffff0000u);
            const unsigned h01 = perm_hi(u1, u0), h23 = perm_hi(u3, u2);
            const unsigned l01 = perm_hi(bc(r1) + 0x8000u, bc(r0) + 0x8000u);
            const unsigned l23 = perm_hi(bc(r3) + 0x8000u, bc(r2) + 0x8000u);
            *(uint2*)(&Ah[row * ASTRIDE + 4 * l]) = uint2{h01, h23};
            *(uint2*)(&Al[row * ASTRIDE + 4 * l]) = uint2{l01, l23};
            const unsigned ut = bc(et[rr]) + 0x8000u;
            const float rt = et[rr] - asf(ut & 0xffff0000u);
            Ah[row * ASTRIDE + 256 + l] = (unsigned short)(ut >> 16);
            Al[row * ASTRIDE + 256 + l] = (unsigned short)((bc(rt) + 0x8000u) >> 16);
        }
        __syncthreads();   // BAR1: A tiles ready

        // ---- prefetch NEXT batch's raw rows (HBM latency hides under GEMM+tail)
        if (bi + GRID < NBATCH) {
            const int b = bi + GRID;
            #pragma unroll
            for (int rr = 0; rr < 4; ++rr) {
                const size_t tok = (size_t)tokens[b * RTOK + row0 + rr];
                const float* src = emb + tok * DIM;
                e4[rr] = *(const float4*)(src + 4 * l);
                et[rr] = tl ? src[256 + l] : 0.f;
            }
        }

        // ---- P1: MFMA GEMM + Gram norms + fused softmax partials
        {
            const int abase = (rb + c) * ASTRIDE + hq * 8;
            const int boff  = (cb + c) * KP + hq * 8;
            f32x4 a0 = {0,0,0,0}, a1 = {0,0,0,0}, a2 = {0,0,0,0};
            f32x4 gv = {0,0,0,0}, g2 = {0,0,0,0};
            __builtin_amdgcn_s_setprio(1);
            #pragma unroll
            for (int t = 0; t < NKS; ++t) {
                const s16x8 bh = *(const s16x8*)(Bh + boff + t * 32);
                const s16x8 bl = *(const s16x8*)(Bl + boff + t * 32);
                const s16x8 ah = *(const s16x8*)(Ah + abase + t * 32);
                const s16x8 al = *(const s16x8*)(Al + abase + t * 32);
                a0 = __builtin_amdgcn_mfma_f32_16x16x32_bf16(ah, bh, a0, 0, 0, 0);
                a1 = __builtin_amdgcn_mfma_f32_16x16x32_bf16(ah, bl, a1, 0, 0, 0);
                a2 = __builtin_amdgcn_mfma_f32_16x16x32_bf16(al, bh, a2, 0, 0, 0);
                gv = __builtin_amdgcn_mfma_f32_16x16x32_bf16(ah, ah, gv, 0, 0, 0);
                g2 = __builtin_amdgcn_mfma_f32_16x16x32_bf16(ah, al, g2, 0, 0, 0);
            }
            __builtin_amdgcn_s_setprio(0);
            if (hq == (c >> 2)) {     // diagonal lanes own |x_row|^2
                const int q = c & 3;
                const float d1 = (q == 0) ? gv[0] : (q == 1) ? gv[1] : (q == 2) ? gv[2] : gv[3];
                const float d2 = (q == 0) ? g2[0] : (q == 1) ? g2[1] : (q == 2) ? g2[2] : g2[3];
                norms[rb + c] = d1 + 2.f * d2;
            }
            asm volatile("s_waitcnt lgkmcnt(0)" ::: "memory");   // intra-wave write->read
            const f32x4 n4 = *(const f32x4*)&norms[rb + hq * 4];
            const int s = (cb + c) & 31;
            float se = 0.f, sv = 0.f;
            #pragma unroll
            for (int q = 0; q < 4; ++q) {
                const float rn = __builtin_amdgcn_rcpf(
                    fmaxf(__builtin_amdgcn_sqrtf(n4[q]), 1e-8f));
                const float v = (a0[q] + a1[q] + a2[q]) * rn;
                const int row = rb + hq * 4 + q;
                smP[(row + 1) * SMST + ch * SMY + (s + 1)] = v;
                const float e = __expf(v);      // |v| <= 1: no max-shift needed
                se += e; sv = fmaf(e, v, sv);
            }
            #pragma unroll
            for (int m = 32; m >= 1; m >>= 1) { se += __shfl_xor(se, m); sv += __shfl_xor(sv, m); }
            if (l == 0) { scrP[w] = se; scrP[8 + w] = sv; }
        }
        __syncthreads();   // BAR2: smP + softmax partials ready, A reads done

        // ---- P2: pl1 border zero + conv1 partials (all threads)
        if (tid >= 446) {
            const int z = tid - 446;
            const int ic = z / 33, rm = z % 33;
            pl1P[ic * 306 + (rm < 17 ? rm : (rm - 16) * 18)] = 0.f;
        }
        float pc[2][4] = {{0,0,0,0},{0,0,0,0}};
        #pragma unroll
        for (int ic = 0; ic < 2; ++ic) {
            float p[4][4];
            #pragma unroll
            for (int a = 0; a < 4; ++a) {
                const int off = (2 * jj + a) * SMST + ic * SMY + 2 * ii;
                const float2 v01 = *(const float2*)&smP[off];
                const float2 v23 = *(const float2*)&smP[off + 2];
                p[a][0] = v01.x; p[a][1] = v01.y; p[a][2] = v23.x; p[a][3] = v23.y;
            }
            #pragma unroll
            for (int py = 0; py < 2; ++py)
            #pragma unroll
            for (int px = 0; px < 2; ++px)
            #pragma unroll
            for (int dy = 0; dy < 3; ++dy)
            #pragma unroll
            for (int dx = 0; dx < 3; ++dx)
                pc[ic][py * 2 + px] += c1w[(oc * 2 + ic) * 9 + dy * 3 + dx] * p[px + dx][py + dy];
        }

        // ---- P3: gate (combine softmax partials) + relu + maxpool -> pl1P
        {
            const f32x4 s0 = *(const f32x4*)&scrP[0];
            const f32x4 s1 = *(const f32x4*)&scrP[4];
            const f32x4 s2 = *(const f32x4*)&scrP[8];
            const f32x4 s3 = *(const f32x4*)&scrP[12];
            const float p0 = (s2.x + s2.y + s3.x + s3.y) / (s0.x + s0.y + s1.x + s1.y);
            const float p1 = (s2.z + s2.w + s3.z + s3.w) / (s0.z + s0.w + s1.z + s1.w);
            const float gg0 = 1.f / (1.f + __expf(-(f2w[0] * p0 + f2w[1] * p1 + f2b[0])));
            const float gg1 = 1.f / (1.f + __expf(-(f2w[2] * p0 + f2w[3] * p1 + f2b[1])));
            const float bias = c1b[oc];
            float mx = 0.f;
            #pragma unroll
            for (int i = 0; i < 4; ++i)
                mx = fmaxf(mx, bias + gg0 * pc[0][i] + gg1 * pc[1][i]);
            pl1P[oc * 306 + (ii + 1) * 18 + (jj + 1)] = mx;
        }
        __syncthreads();   // BAR4: pl1P ready

        // ---- P4: waves 0-1: conv2(2x2,pad1)+relu+avgpool2 + fc partials
        if (w < 2) {
            const int oc2 = w, ii2 = l >> 3, jj2 = l & 7;
            float sum = 0.f;
            #pragma unroll
            for (int py = 0; py < 2; ++py)
            #pragma unroll
            for (int px = 0; px < 2; ++px) {
                const int y = 2 * ii2 + py, x = 2 * jj2 + px;
                float acc = c2b[oc2];
                #pragma unroll
                for (int ic = 0; ic < 2; ++ic)
                #pragma unroll
                for (int dy = 0; dy < 2; ++dy)
                #pragma unroll
                for (int dx = 0; dx < 2; ++dx)
                    acc += c2w[((oc2 * 2 + ic) * 2 + dy) * 2 + dx] *
                           pl1P[ic * 306 + (y + dy) * 18 + (x + dx)];
                sum += fmaxf(acc, 0.f);
            }
            const float val = 0.25f * sum;
            const int o = w * 64 + l;
            float t0 = val * fcw[o];
            float t1 = val * fcw[128 + o];
            #pragma unroll
            for (int m = 32; m >= 1; m >>= 1) { t0 += __shfl_xor(t0, m); t1 += __shfl_xor(t1, m); }
            if (l == 0) { scr2[w] = t0; scr2[2 + w] = t1; }
        }
        __syncthreads();   // BAR5: scr2 ready; pl1P(=Ah) free for next pack

        if (tid == 0) {
            out[bi * 2 + 0] = fcb[0] + scr2[0] + scr2[1];
            out[bi * 2 + 1] = fcb[1] + scr2[2] + scr2[3];
        }
    }
}

extern "C" void kernel_launch(void* const* d_in, const int* in_sizes, int n_in,
                              void* d_out, int out_size, void* d_ws, size_t ws_size,
                              hipStream_t stream) {
    const int* tokens = (const int*)d_in[0];
    const int* sidx   = (const int*)d_in[1];
    const float* emb  = (const float*)d_in[2];
    const float* c1w  = (const float*)d_in[3];
    const float* c1b  = (const float*)d_in[4];
    const float* c2w  = (const float*)d_in[5];
    const float* c2b  = (const float*)d_in[6];
    const float* f2w  = (const float*)d_in[7];
    const float* f2b  = (const float*)d_in[8];
    const float* fcw  = (const float*)d_in[9];
    const float* fcb  = (const float*)d_in[10];

    unsigned short* Bh = (unsigned short*)d_ws;
    unsigned short* Bl = Bh + NSUP * KP;

    prep_kernel<<<NSUP, 64, 0, stream>>>(sidx, emb, Bh, Bl);
    main_kernel<<<GRID, 512, 0, stream>>>(tokens, emb, Bh, Bl,
                                          c1w, c1b, c2w, c2b,
                                          f2w, f2b, fcw, fcb, (float*)d_out);
}

// Round 6
// 100.383 us; speedup vs baseline: 3.4397x; 3.4397x over previous
//
#include <hip/hip_runtime.h>
#include <stdint.h>

#define DIM     300
#define NBATCH  4096
#define RTOK    32
#define NSUP    64      // N*S = 2*32 support cols
#define KP      320     // K padded to 10*32
#define NKS     10      // K steps of 32
#define ASTRIDE 328     // LDS row stride (ushort) for A tiles (16B-aligned rows)
#define SMST    82      // padded sm tile x-stride (floats)
#define SMY     36      // per-channel y extent

typedef float f32x4 __attribute__((ext_vector_type(4)));
typedef short s16x8 __attribute__((ext_vector_type(8)));

static __device__ __forceinline__ unsigned bc(float x) { return __builtin_bit_cast(unsigned, x); }
static __device__ __forceinline__ float asf(unsigned u) { return __builtin_bit_cast(float, u); }
static __device__ __forceinline__ unsigned perm_hi(unsigned a, unsigned b) {
    return __builtin_amdgcn_perm(a, b, 0x07060302u);   // [a.hi16 : b.hi16]
}
static __device__ __forceinline__ unsigned short f2bf(float x) {   // RNE (prep only)
    unsigned u = bc(x);
    return (unsigned short)((u + 0x7FFFu + ((u >> 16) & 1u)) >> 16);
}
static __device__ __forceinline__ float bf2f(unsigned short h) { return asf((unsigned)h << 16); }

// ---------------- kernel 1: normalize support vectors -> bf16 hi/lo [64][320]
__global__ __launch_bounds__(64) void prep_kernel(
    const int* __restrict__ sidx, const float* __restrict__ emb,
    unsigned short* __restrict__ Bh, unsigned short* __restrict__ Bl) {
    const int j = blockIdx.x, l = threadIdx.x;
    const size_t tok = (size_t)sidx[j];
    const float* src = emb + tok * DIM;
    float e[5];
    #pragma unroll
    for (int c = 0; c < 5; ++c) {
        const int k = c * 64 + l;
        e[c] = (k < DIM) ? src[k] : 0.f;
    }
    float s = e[0]*e[0] + e[1]*e[1] + e[2]*e[2] + e[3]*e[3] + e[4]*e[4];
    #pragma unroll
    for (int m = 32; m >= 1; m >>= 1) s += __shfl_xor(s, m);
    const float rn = 1.f / fmaxf(sqrtf(s), 1e-8f);
    #pragma unroll
    for (int c = 0; c < 5; ++c) {
        const int k = c * 64 + l;
        const float v = (k < DIM) ? e[c] * rn : 0.f;
        const unsigned short h = f2bf(v);
        Bh[j * KP + k] = h;
        Bl[j * KP + k] = f2bf(v - bf2f(h));
    }
}

// ---------------- kernel 2: fused gather + split-bf16 MFMA GEMM (+Gram norms) + tail
__global__ __launch_bounds__(512)
__attribute__((amdgpu_waves_per_eu(6, 6)))
void main_kernel(
    const int* __restrict__ tokens, const float* __restrict__ emb,
    const unsigned short* __restrict__ Bh, const unsigned short* __restrict__ Bl,
    const float* __restrict__ c1w, const float* __restrict__ c1b,
    const float* __restrict__ c2w, const float* __restrict__ c2b,
    const float* __restrict__ f2w, const float* __restrict__ f2b,
    const float* __restrict__ fcw, const float* __restrict__ fcb,
    float* __restrict__ out) {

    __shared__ __attribute__((aligned(16))) unsigned short Ah[32 * ASTRIDE];
    __shared__ __attribute__((aligned(16))) unsigned short Al[32 * ASTRIDE];
    __shared__ __attribute__((aligned(16))) float smP[34 * SMST];  // [xp=r+1][ch][yp=s+1]
    __shared__ __attribute__((aligned(16))) float norms[32];
    __shared__ __attribute__((aligned(16))) float scrP[16];  // [0..7]=se_w [8..15]=sv_w
    float* pl1P = (float*)Ah;   // overlay: [2][17][18] zero-bordered pool1

    const int tid = threadIdx.x;
    const int w = tid >> 6, l = tid & 63;
    const int batch = blockIdx.x;
    const int cb = (w & 3) * 16, rb = (w >> 2) * 16;
    const int c = l & 15, hq = l >> 4;
    const int ch = (w & 3) >> 1;          // softmax/sm channel of this wave's tile
    const int row0 = w * 4;
    const bool tl = (l < DIM - 256);      // tail lanes 0..43
    const int oc = tid >> 8, ii = (tid >> 4) & 15, jj = tid & 15;

    // ---- P0a: issue gather loads (HBM) first
    float4 e4[4]; float et[4];
    #pragma unroll
    for (int rr = 0; rr < 4; ++rr) {
        const size_t tok = (size_t)tokens[batch * RTOK + row0 + rr];
        const float* src = emb + tok * DIM;
        e4[rr] = *(const float4*)(src + 4 * l);
        et[rr] = tl ? src[256 + l] : 0.f;
    }

    // ---- P0b: clear smP while loads fly (697 float4 chunks)
    {
        const f32x4 z = {0.f, 0.f, 0.f, 0.f};
        ((f32x4*)smP)[tid] = z;
        if (tid < 697 - 512) ((f32x4*)smP)[512 + tid] = z;
    }

    // ---- P0c: pack gathered rows to split-bf16, store A tiles
    #pragma unroll
    for (int rr = 0; rr < 4; ++rr) {
        const int row = row0 + rr;
        // round-half-up hi (lo captures the rounding error exactly)
        const unsigned u0 = bc(e4[rr].x) + 0x8000u, u1 = bc(e4[rr].y) + 0x8000u;
        const unsigned u2 = bc(e4[rr].z) + 0x8000u, u3 = bc(e4[rr].w) + 0x8000u;
        const float r0 = e4[rr].x - asf(u0 & 0xffff0000u);
        const float r1 = e4[rr].y - asf(u1 & 0xffff0000u);
        const float r2 = e4[rr].z - asf(u2 & 0xffff0000u);
        const float r3 = e4[rr].w - asf(u3 & 0xffff0000u);
        const unsigned h01 = perm_hi(u1, u0), h23 = perm_hi(u3, u2);
        const unsigned l01 = perm_hi(bc(r1) + 0x8000u, bc(r0) + 0x8000u);
        const unsigned l23 = perm_hi(bc(r3) + 0x8000u, bc(r2) + 0x8000u);
        *(uint2*)(&Ah[row * ASTRIDE + 4 * l]) = uint2{h01, h23};
        *(uint2*)(&Al[row * ASTRIDE + 4 * l]) = uint2{l01, l23};
        const unsigned ut = bc(et[rr]) + 0x8000u;
        const float rt = et[rr] - asf(ut & 0xffff0000u);
        Ah[row * ASTRIDE + 256 + l] = (unsigned short)(ut >> 16);
        Al[row * ASTRIDE + 256 + l] = (unsigned short)((bc(rt) + 0x8000u) >> 16);
    }
    __syncthreads();   // BAR1: A tiles ready

    // ---- P1: MFMA GEMM + Gram-diag norms + fused softmax partials
    {
        const int abase = (rb + c) * ASTRIDE + hq * 8;
        const int boff  = (cb + c) * KP + hq * 8;
        f32x4 a0 = {0,0,0,0}, a1 = {0,0,0,0}, a2 = {0,0,0,0};
        f32x4 gv = {0,0,0,0}, g2 = {0,0,0,0};
        __builtin_amdgcn_s_setprio(1);
        #pragma unroll
        for (int t = 0; t < NKS; ++t) {
            const s16x8 bh = *(const s16x8*)(Bh + boff + t * 32);
            const s16x8 bl = *(const s16x8*)(Bl + boff + t * 32);
            const s16x8 ah = *(const s16x8*)(Ah + abase + t * 32);
            const s16x8 al = *(const s16x8*)(Al + abase + t * 32);
            a0 = __builtin_amdgcn_mfma_f32_16x16x32_bf16(ah, bh, a0, 0, 0, 0);
            a1 = __builtin_amdgcn_mfma_f32_16x16x32_bf16(ah, bl, a1, 0, 0, 0);
            a2 = __builtin_amdgcn_mfma_f32_16x16x32_bf16(al, bh, a2, 0, 0, 0);
            gv = __builtin_amdgcn_mfma_f32_16x16x32_bf16(ah, ah, gv, 0, 0, 0);
            g2 = __builtin_amdgcn_mfma_f32_16x16x32_bf16(ah, al, g2, 0, 0, 0);
        }
        __builtin_amdgcn_s_setprio(0);
        if (hq == (c >> 2)) {     // diagonal lanes own |x_row|^2
            const int q = c & 3;
            const float d1 = (q == 0) ? gv[0] : (q == 1) ? gv[1] : (q == 2) ? gv[2] : gv[3];
            const float d2 = (q == 0) ? g2[0] : (q == 1) ? g2[1] : (q == 2) ? g2[2] : g2[3];
            norms[rb + c] = d1 + 2.f * d2;
        }
        asm volatile("s_waitcnt lgkmcnt(0)" ::: "memory");   // intra-wave write->read
        const f32x4 n4 = *(const f32x4*)&norms[rb + hq * 4];
        const int s = (cb + c) & 31;
        float se = 0.f, sv = 0.f;
        #pragma unroll
        for (int q = 0; q < 4; ++q) {
            const float rn = __builtin_amdgcn_rcpf(
                fmaxf(__builtin_amdgcn_sqrtf(n4[q]), 1e-8f));
            const float v = (a0[q] + a1[q] + a2[q]) * rn;
            smP[(rb + hq * 4 + q + 1) * SMST + ch * SMY + (s + 1)] = v;
            const float e = __expf(v);      // |v| <= 1: no max-shift needed
            se += e; sv = fmaf(e, v, sv);
        }
        #pragma unroll
        for (int m = 32; m >= 1; m >>= 1) { se += __shfl_xor(se, m); sv += __shfl_xor(sv, m); }
        if (l == 0) { scrP[w] = se; scrP[8 + w] = sv; }
    }
    __syncthreads();   // BAR2: smP + softmax partials ready; A-frag reads done

    // ---- P2: pl1 border zero + conv1 partials + gate + relu + maxpool -> pl1P
    if (tid >= 446) {   // zero pl1P borders: yp=0 row (17) + xp=0 col (16), x2 channels
        const int z = tid - 446;
        const int ic = z / 33, rm = z % 33;
        pl1P[ic * 306 + (rm < 17 ? rm : (rm - 16) * 18)] = 0.f;
    }
    {
        float pc[2][4] = {{0,0,0,0},{0,0,0,0}};
        #pragma unroll
        for (int ic = 0; ic < 2; ++ic) {
            float p[4][4];
            #pragma unroll
            for (int a = 0; a < 4; ++a) {        // xp = 2jj+a, yp base 2ii
                const int off = (2 * jj + a) * SMST + ic * SMY + 2 * ii;
                const float2 v01 = *(const float2*)&smP[off];
                const float2 v23 = *(const float2*)&smP[off + 2];
                p[a][0] = v01.x; p[a][1] = v01.y; p[a][2] = v23.x; p[a][3] = v23.y;
            }
            #pragma unroll
            for (int py = 0; py < 2; ++py)
            #pragma unroll
            for (int px = 0; px < 2; ++px)
            #pragma unroll
            for (int dy = 0; dy < 3; ++dy)
            #pragma unroll
            for (int dx = 0; dx < 3; ++dx)
                pc[ic][py * 2 + px] += c1w[(oc * 2 + ic) * 9 + dy * 3 + dx] * p[px + dx][py + dy];
        }
        // gate from fused-softmax partials
        const f32x4 s0 = *(const f32x4*)&scrP[0];
        const f32x4 s1 = *(const f32x4*)&scrP[4];
        const f32x4 s2 = *(const f32x4*)&scrP[8];
        const f32x4 s3 = *(const f32x4*)&scrP[12];
        const float p0 = (s2.x + s2.y + s3.x + s3.y) / (s0.x + s0.y + s1.x + s1.y);
        const float p1 = (s2.z + s2.w + s3.z + s3.w) / (s0.z + s0.w + s1.z + s1.w);
        const float gg0 = 1.f / (1.f + __expf(-(f2w[0] * p0 + f2w[1] * p1 + f2b[0])));
        const float gg1 = 1.f / (1.f + __expf(-(f2w[2] * p0 + f2w[3] * p1 + f2b[1])));
        const float bias = c1b[oc];
        float mx = 0.f;    // relu folded: start at 0
        #pragma unroll
        for (int i = 0; i < 4; ++i)
            mx = fmaxf(mx, bias + gg0 * pc[0][i] + gg1 * pc[1][i]);
        pl1P[oc * 306 + (ii + 1) * 18 + (jj + 1)] = mx;
    }
    __syncthreads();   // BAR3: pl1P ready

    // ---- P3: wave 0: conv2(2x2,pad1)+relu+avgpool2 + fc -> out (no more barriers)
    if (w == 0) {
        float o0 = 0.f, o1 = 0.f;
        #pragma unroll
        for (int h = 0; h < 2; ++h) {
            const int o = h * 64 + l, oc2 = o >> 6, ii2 = (o >> 3) & 7, jj2 = o & 7;
            float sum = 0.f;
            #pragma unroll
            for (int py = 0; py < 2; ++py)
            #pragma unroll
            for (int px = 0; px < 2; ++px) {
                const int y = 2 * ii2 + py, x = 2 * jj2 + px;
                float acc = c2b[oc2];
                #pragma unroll
                for (int ic = 0; ic < 2; ++ic)
                #pragma unroll
                for (int dy = 0; dy < 2; ++dy)
                #pragma unroll
                for (int dx = 0; dx < 2; ++dx)
                    acc += c2w[((oc2 * 2 + ic) * 2 + dy) * 2 + dx] *
                           pl1P[ic * 306 + (y + dy) * 18 + (x + dx)];
                sum += fmaxf(acc, 0.f);
            }
            const float val = 0.25f * sum;
            o0 = fmaf(val, fcw[o], o0);
            o1 = fmaf(val, fcw[128 + o], o1);
        }
        #pragma unroll
        for (int m = 32; m >= 1; m >>= 1) { o0 += __shfl_xor(o0, m); o1 += __shfl_xor(o1, m); }
        if (l == 0) {
            out[batch * 2 + 0] = fcb[0] + o0;
            out[batch * 2 + 1] = fcb[1] + o1;
        }
    }
}

extern "C" void kernel_launch(void* const* d_in, const int* in_sizes, int n_in,
                              void* d_out, int out_size, void* d_ws, size_t ws_size,
                              hipStream_t stream) {
    const int* tokens = (const int*)d_in[0];
    const int* sidx   = (const int*)d_in[1];
    const float* emb  = (const float*)d_in[2];
    const float* c1w  = (const float*)d_in[3];
    const float* c1b  = (const float*)d_in[4];
    const float* c2w  = (const float*)d_in[5];
    const float* c2b  = (const float*)d_in[6];
    const float* f2w  = (const float*)d_in[7];
    const float* f2b  = (const float*)d_in[8];
    const float* fcw  = (const float*)d_in[9];
    const float* fcb  = (const float*)d_in[10];

    unsigned short* Bh = (unsigned short*)d_ws;
    unsigned short* Bl = Bh + NSUP * KP;

    prep_kernel<<<NSUP, 64, 0, stream>>>(sidx, emb, Bh, Bl);
    main_kernel<<<NBATCH, 512, 0, stream>>>(tokens, emb, Bh, Bl,
                                            c1w, c1b, c2w, c2b,
                                            f2w, f2b, fcw, fcb, (float*)d_out);
}